// Round 1
// baseline (4417.227 us; speedup 1.0000x reference)
//
#include <hip/hip_runtime.h>
#include <stdint.h>

#define HH 100
#define WW 100
#define NPIX 10000
#define CIN 1024
#define COUT 1024
#define NA 9
#define NANCH 90000
#define PRE 6000
#define POST 300
#define SORTN 131072
#define MASKW 96   // u64 words per mask row (94 used, padded)
#define NW 94      // ceil(6000/64)

// ---------------------------------------------------------------------------
// Kernel 1: 3x3 conv (1024->1024, SAME, zero pad) + bias + ReLU. fp32 VALU.
// Tile: 8x8 pixels x 64 out-channels per block. 256 threads, 16 acc/thread.
// ---------------------------------------------------------------------------
__global__ __launch_bounds__(256) void conv3x3_relu(
    const float* __restrict__ x, const float* __restrict__ w1,
    const float* __restrict__ b1, float* __restrict__ y)
{
    __shared__ __align__(16) float xt[2][10][12];
    __shared__ __align__(16) float wt[2][9][64];
    const int cog = blockIdx.x;            // 0..15 -> co tile
    const int pt  = blockIdx.y;            // 0..168 -> pixel tile (13x13)
    const int ty0 = (pt / 13) * 8;
    const int tx0 = (pt % 13) * 8;
    const int t   = threadIdx.x;
    const int co0 = cog * 64;
    const int c4  = (t & 15) * 4;          // co_local base (0..60)
    const int q   = t >> 4;                // 0..15
    const int pyl = q >> 1;                // 0..7
    const int pxl = (q & 1) * 4;           // 0 or 4

    float acc[4][4];
#pragma unroll
    for (int j = 0; j < 4; ++j)
#pragma unroll
        for (int c = 0; c < 4; ++c) acc[j][c] = 0.f;

    for (int ci0 = 0; ci0 < CIN; ci0 += 2) {
        __syncthreads();
        // stage x halo: 2 ci x 10x10 (zero-padded at borders)
        if (t < 200) {
            int cc = t / 100, rc = t % 100;
            int r = rc / 10, c = rc % 10;
            int gy = ty0 - 1 + r, gx = tx0 - 1 + c;
            float v = 0.f;
            if (gy >= 0 && gy < HH && gx >= 0 && gx < WW)
                v = x[(ci0 + cc) * NPIX + gy * WW + gx];
            xt[cc][r][c] = v;
        }
        // stage w: 2 ci x 9 taps x 64 co
        for (int e = t; e < 1152; e += 256) {
            int cc = e / 576, rem = e % 576;
            int col = rem / 9, tap = rem % 9;
            wt[cc][tap][col] = w1[(size_t)(co0 + col) * (CIN * 9) + (ci0 + cc) * 9 + tap];
        }
        __syncthreads();
#pragma unroll
        for (int cc = 0; cc < 2; ++cc) {
#pragma unroll
            for (int kh = 0; kh < 3; ++kh) {
                float x8[8];
                float4 xa = *(const float4*)&xt[cc][pyl + kh][pxl];
                float4 xb = *(const float4*)&xt[cc][pyl + kh][pxl + 4];
                x8[0]=xa.x; x8[1]=xa.y; x8[2]=xa.z; x8[3]=xa.w;
                x8[4]=xb.x; x8[5]=xb.y; x8[6]=xb.z; x8[7]=xb.w;
#pragma unroll
                for (int kw = 0; kw < 3; ++kw) {
                    float4 wv = *(const float4*)&wt[cc][kh * 3 + kw][c4];
#pragma unroll
                    for (int j = 0; j < 4; ++j) {
                        float xv = x8[j + kw];
                        acc[j][0] += xv * wv.x;
                        acc[j][1] += xv * wv.y;
                        acc[j][2] += xv * wv.z;
                        acc[j][3] += xv * wv.w;
                    }
                }
            }
        }
    }
    const int gy = ty0 + pyl;
    if (gy < HH) {
#pragma unroll
        for (int j = 0; j < 4; ++j) {
            int gx = tx0 + pxl + j;
            if (gx < WW) {
#pragma unroll
                for (int c = 0; c < 4; ++c) {
                    float v = acc[j][c] + b1[co0 + c4 + c];
                    y[(size_t)(co0 + c4 + c) * NPIX + gy * WW + gx] = fmaxf(v, 0.f);
                }
            }
        }
    }
}

// ---------------------------------------------------------------------------
// Kernel 2: fused 1x1 convs (cls 9ch + box 36ch) + sigmoid + box decode +
// clip + sort-key pack. One thread per anchor; grid padded to SORTN.
// ---------------------------------------------------------------------------
__global__ __launch_bounds__(256) void rpn_head(
    const float* __restrict__ y,
    const float* __restrict__ wcls, const float* __restrict__ bcls,
    const float* __restrict__ wbox, const float* __restrict__ bbox,
    const float* __restrict__ am, const int* __restrict__ ishape,
    float* __restrict__ out_scores, float* __restrict__ out_deltas,
    float4* __restrict__ boxes, unsigned long long* __restrict__ keys)
{
    __shared__ float wlds[8][46];
    const int t = threadIdx.x;
    const int i = blockIdx.x * 256 + t;
    if (blockIdx.x * 256 >= NANCH) {       // pure padding block
        if (i < SORTN) keys[i] = 0ull;
        return;
    }
    const int ia = (i < NANCH) ? i : (NANCH - 1);
    const int p = ia / NA, a = ia % NA;
    float acc[5] = {0.f, 0.f, 0.f, 0.f, 0.f};
    for (int c0 = 0; c0 < CIN; c0 += 8) {
        __syncthreads();
        for (int e = t; e < 360; e += 256) {
            int ch = e % 45, cc = e / 45;
            wlds[cc][ch] = (ch < 9) ? wcls[ch * CIN + c0 + cc]
                                    : wbox[(ch - 9) * CIN + c0 + cc];
        }
        __syncthreads();
#pragma unroll
        for (int cc = 0; cc < 8; ++cc) {
            float yv = y[(size_t)(c0 + cc) * NPIX + p];
            acc[0] += yv * wlds[cc][a];
#pragma unroll
            for (int c = 0; c < 4; ++c)
                acc[1 + c] += yv * wlds[cc][9 + 4 * a + c];
        }
    }
    if (i >= NANCH) { if (i < SORTN) keys[i] = 0ull; return; }

    float logit = acc[0] + bcls[a];
    float score = 1.f / (1.f + expf(-logit));
    float d0 = acc[1] + bbox[4 * a + 0];
    float d1 = acc[2] + bbox[4 * a + 1];
    float d2 = acc[3] + bbox[4 * a + 2];
    float d3 = acc[4] + bbox[4 * a + 3];
    out_scores[i] = score;
    out_deltas[i * 4 + 0] = d0;
    out_deltas[i * 4 + 1] = d1;
    out_deltas[i * 4 + 2] = d2;
    out_deltas[i * 4 + 3] = d3;

    float cy = am[i * 4 + 0], cx = am[i * 4 + 1];
    float ah = am[i * 4 + 2], aw = am[i * 4 + 3];
    float ctry = cy + d0 * ah, ctrx = cx + d1 * aw;
    float hh = ah * expf(d2), ww = aw * expf(d3);
    float y1 = ctry - 0.5f * hh, x1 = ctrx - 0.5f * ww;
    float y2 = ctry + 0.5f * hh, x2 = ctrx + 0.5f * ww;
    float imh = (float)ishape[1], imw = (float)ishape[2];
    y1 = fmaxf(y1, 0.f); x1 = fmaxf(x1, 0.f);
    y2 = fminf(y2, imh); x2 = fminf(x2, imw);
    boxes[i] = make_float4(y1, x1, y2, x2);
    unsigned sb = __float_as_uint(score);  // score > 0 -> monotone bits
    keys[i] = ((unsigned long long)sb << 32) | (unsigned)i;  // tie: idx desc
}

// ---------------------------------------------------------------------------
// Bitonic sort (descending) of SORTN u64 keys.
// ---------------------------------------------------------------------------
__global__ __launch_bounds__(256) void bitonic_local(unsigned long long* keys)
{
    __shared__ unsigned long long s[2048];
    const int base = blockIdx.x * 2048, t = threadIdx.x;
    for (int k = t; k < 2048; k += 256) s[k] = keys[base + k];
    for (int L = 2; L <= 2048; L <<= 1) {
        for (int d = L >> 1; d >= 1; d >>= 1) {
            __syncthreads();
            for (int pr = t; pr < 1024; pr += 256) {
                int i = ((pr & ~(d - 1)) << 1) | (pr & (d - 1));
                int j = i + d;
                bool desc = (((base + i) & L) == 0);
                unsigned long long va = s[i], vb = s[j];
                bool sw = desc ? (va < vb) : (va > vb);
                if (sw) { s[i] = vb; s[j] = va; }
            }
        }
    }
    __syncthreads();
    for (int k = t; k < 2048; k += 256) keys[base + k] = s[k];
}

__global__ __launch_bounds__(256) void bitonic_gpass(unsigned long long* keys, int L, int d)
{
    int pr = blockIdx.x * 256 + threadIdx.x;       // SORTN/2 pairs
    int i = ((pr & ~(d - 1)) << 1) | (pr & (d - 1));
    int j = i + d;
    bool desc = ((i & L) == 0);
    unsigned long long va = keys[i], vb = keys[j];
    bool sw = desc ? (va < vb) : (va > vb);
    if (sw) { keys[i] = vb; keys[j] = va; }
}

__global__ __launch_bounds__(256) void bitonic_lmerge(unsigned long long* keys, int L)
{
    __shared__ unsigned long long s[2048];
    const int base = blockIdx.x * 2048, t = threadIdx.x;
    for (int k = t; k < 2048; k += 256) s[k] = keys[base + k];
    const bool desc = ((base & L) == 0);
    for (int d = 1024; d >= 1; d >>= 1) {
        __syncthreads();
        for (int pr = t; pr < 1024; pr += 256) {
            int i = ((pr & ~(d - 1)) << 1) | (pr & (d - 1));
            int j = i + d;
            unsigned long long va = s[i], vb = s[j];
            bool sw = desc ? (va < vb) : (va > vb);
            if (sw) { s[i] = vb; s[j] = va; }
        }
    }
    __syncthreads();
    for (int k = t; k < 2048; k += 256) keys[base + k] = s[k];
}

// ---------------------------------------------------------------------------
// Gather top-6000 boxes in sorted order; validity bitmask via ballot.
// ---------------------------------------------------------------------------
__global__ __launch_bounds__(256) void gather_sorted(
    const unsigned long long* __restrict__ keys, const float4* __restrict__ boxes,
    float4* __restrict__ box_s, unsigned long long* __restrict__ validw)
{
    int s = blockIdx.x * 256 + threadIdx.x;        // 24 blocks -> 6144
    bool valid = false;
    if (s < PRE) {
        unsigned idx = (unsigned)(keys[s] & 0xffffffffull);
        float4 b = boxes[idx];
        box_s[s] = b;
        valid = ((b.z - b.x) >= 16.f) && ((b.w - b.y) >= 16.f);
    }
    unsigned long long bal = __ballot(valid);
    if ((threadIdx.x & 63) == 0) validw[s >> 6] = bal;
}

// ---------------------------------------------------------------------------
// Suppression bitmask: mask[i] bit j = (IOU(i,j) > 0.7) && (j > i)
// ---------------------------------------------------------------------------
__global__ __launch_bounds__(128) void nms_mask(
    const float4* __restrict__ box_s, unsigned long long* __restrict__ mask)
{
    const int i = blockIdx.x;
    const int w = threadIdx.x;
    if (w >= NW) return;
    float4 bi = box_s[i];
    float areai = (bi.z - bi.x) * (bi.w - bi.y);
    unsigned long long m = 0ull;
    const int j0 = w * 64;
    if (j0 + 63 > i) {
#pragma unroll 4
        for (int b = 0; b < 64; ++b) {
            int j = j0 + b;
            if (j <= i || j >= PRE) continue;
            float4 bj = box_s[j];
            float areaj = (bj.z - bj.x) * (bj.w - bj.y);
            float iy1 = fmaxf(bi.x, bj.x), ix1 = fmaxf(bi.y, bj.y);
            float iy2 = fminf(bi.z, bj.z), ix2 = fminf(bi.w, bj.w);
            float inter = fmaxf(iy2 - iy1, 0.f) * fmaxf(ix2 - ix1, 0.f);
            float iou = inter / (areai + areaj - inter + 1e-8f);
            if (iou > 0.7f) m |= (1ull << b);
        }
    }
    mask[(size_t)i * MASKW + w] = m;
}

// ---------------------------------------------------------------------------
// Sequential greedy NMS scan. Single wave; removed-set in 2 regs/lane.
// 16-deep row prefetch ring; early exit once >= POST keeps.
// ---------------------------------------------------------------------------
__global__ __launch_bounds__(64) void nms_scan(
    const unsigned long long* __restrict__ mask,
    const unsigned long long* __restrict__ validw,
    unsigned long long* __restrict__ keepw)
{
    const int l = threadIdx.x;
    unsigned long long r0 = ~validw[l];
    unsigned long long r1 = (l < NW - 64) ? ~validw[64 + l] : ~0ull;

    unsigned long long p0[16], p1[16];
#pragma unroll
    for (int k = 0; k < 16; ++k) {
        p0[k] = mask[(size_t)k * MASKW + l];
        p1[k] = (l < NW - 64) ? mask[(size_t)k * MASKW + 64 + l] : 0ull;
    }
    int kept = 0;
    for (int w = 0; w < NW && kept < POST; ++w) {
        unsigned long long Wc = (w < 64) ? __shfl(r0, w) : __shfl(r1, w - 64);
#pragma unroll 16
        for (int b = 0; b < 64; ++b) {
            int i = w * 64 + b;
            if (i >= PRE) break;
            int slot = i & 15;
            unsigned long long m0 = p0[slot], m1 = p1[slot];
            int nxt = i + 16;
            if (nxt < PRE) {
                p0[slot] = mask[(size_t)nxt * MASKW + l];
                p1[slot] = (l < NW - 64) ? mask[(size_t)nxt * MASKW + 64 + l] : 0ull;
            }
            if (!((Wc >> b) & 1ull)) {
                r0 |= m0; r1 |= m1;
                Wc = (w < 64) ? __shfl(r0, w) : __shfl(r1, w - 64);
                ++kept;
            }
        }
    }
    keepw[l] = ~r0;
    if (l < NW - 64) keepw[64 + l] = ~r1;
}

// ---------------------------------------------------------------------------
// Emit first POST kept boxes in order; zero-fill rest.
// ---------------------------------------------------------------------------
__global__ __launch_bounds__(256) void out_gather(
    const unsigned long long* __restrict__ keepw,
    const float4* __restrict__ box_s, float* __restrict__ outp)
{
    __shared__ unsigned long long kw_s[NW];
    __shared__ int prefix[NW];
    const int t = threadIdx.x;
    if (t < NW) kw_s[t] = keepw[t];
    __syncthreads();
    if (t == 0) {
        int cum = 0;
        for (int w = 0; w < NW; ++w) { prefix[w] = cum; cum += __popcll(kw_s[w]); }
    }
    for (int k = t; k < POST * 4; k += 256) outp[k] = 0.f;
    __syncthreads();
    for (int i = t; i < PRE; i += 256) {
        int w = i >> 6, b = i & 63;
        unsigned long long kw = kw_s[w];
        if ((kw >> b) & 1ull) {
            int rank = prefix[w] + __popcll(kw & ((1ull << b) - 1ull));
            if (rank < POST) {
                float4 bx = box_s[i];
                outp[rank * 4 + 0] = bx.x;
                outp[rank * 4 + 1] = bx.y;
                outp[rank * 4 + 2] = bx.z;
                outp[rank * 4 + 3] = bx.w;
            }
        }
    }
}

// ---------------------------------------------------------------------------
extern "C" void kernel_launch(void* const* d_in, const int* in_sizes, int n_in,
                              void* d_out, int out_size, void* d_ws, size_t ws_size,
                              hipStream_t stream)
{
    const float* x      = (const float*)d_in[0];
    const int*   ishape = (const int*)  d_in[1];
    const float* am     = (const float*)d_in[2];
    // d_in[3] anchor_valid_map (unused by reference), d_in[4]/d_in[5] pre/post (fixed 6000/300)
    const float* w1   = (const float*)d_in[6];
    const float* b1   = (const float*)d_in[7];
    const float* wcls = (const float*)d_in[8];
    const float* bcls = (const float*)d_in[9];
    const float* wbox = (const float*)d_in[10];
    const float* bbox = (const float*)d_in[11];
    float* out = (float*)d_out;

    char* ws = (char*)d_ws;
    size_t off = 0;
    float* y = (float*)(ws + off);                    off += (size_t)COUT * NPIX * 4;   // 40.96 MB
    float4* boxes = (float4*)(ws + off);              off += (size_t)NANCH * 16;        // 1.44 MB
    unsigned long long* keys = (unsigned long long*)(ws + off); off += (size_t)SORTN * 8; // 1.05 MB
    float4* box_s = (float4*)(ws + off);              off += (size_t)PRE * 16;          // 96 KB
    unsigned long long* validw = (unsigned long long*)(ws + off); off += 96 * 8;
    unsigned long long* keepw  = (unsigned long long*)(ws + off); off += 96 * 8;
    unsigned long long* maskb  = (unsigned long long*)(ws + off); off += (size_t)PRE * MASKW * 8; // 4.6 MB

    conv3x3_relu<<<dim3(16, 169), 256, 0, stream>>>(x, w1, b1, y);
    rpn_head<<<SORTN / 256, 256, 0, stream>>>(y, wcls, bcls, wbox, bbox, am, ishape,
                                              out, out + NANCH, boxes, keys);
    bitonic_local<<<SORTN / 2048, 256, 0, stream>>>(keys);
    for (int L = 4096; L <= SORTN; L <<= 1) {
        for (int d = L >> 1; d >= 2048; d >>= 1)
            bitonic_gpass<<<SORTN / 512, 256, 0, stream>>>(keys, L, d);
        bitonic_lmerge<<<SORTN / 2048, 256, 0, stream>>>(keys, L);
    }
    gather_sorted<<<24, 256, 0, stream>>>(keys, boxes, box_s, validw);
    nms_mask<<<PRE, 128, 0, stream>>>(box_s, maskb);
    nms_scan<<<1, 64, 0, stream>>>(maskb, validw, keepw);
    out_gather<<<1, 256, 0, stream>>>(keepw, box_s, out + (size_t)NANCH * 5);
}

// Round 2
// 4007.209 us; speedup vs baseline: 1.1023x; 1.1023x over previous
//
#include <hip/hip_runtime.h>
#include <stdint.h>

#define HH 100
#define WW 100
#define NPIX 10000
#define CIN 1024
#define COUT 1024
#define NA 9
#define NANCH 90000
#define PRE 6000
#define POST 300
#define SORTN 131072
#define MASKW 96   // u64 words per mask row (94 used, padded)
#define NW 94      // ceil(6000/64)

#define TILE_R 8
#define TILE_C 16
#define NTR 13     // ceil(100/8)
#define NTC 7      // ceil(100/16)

// ---------------------------------------------------------------------------
// Kernel 1: 3x3 conv (1024->1024, SAME) + bias + ReLU. fp32 VALU, register-
// tiled: block = 8x16 px x 64 co, 128 thr; per-thread 4x4 px x 4 co = 64 acc.
// ci-step 4; all staging offsets hoisted (no div/mod in K-loop).
// ---------------------------------------------------------------------------
__global__ __launch_bounds__(128, 3) void conv3x3_relu(
    const float* __restrict__ x, const float* __restrict__ w1,
    const float* __restrict__ b1, float* __restrict__ y)
{
    __shared__ __align__(16) float xs[4 * 10 * 20];   // [cc][ir 0..9][pitch 20]
    __shared__ __align__(16) float ws[4 * 9 * 64];    // [cc][tap][col]
    const int t    = threadIdx.x;
    const int cog  = blockIdx.x;          // 0..15
    const int tile = blockIdx.y;          // 0..90
    const int tr = tile / NTC, tcc_ = tile % NTC;
    const int ty0 = tr * TILE_R, tx0 = tcc_ * TILE_C;
    const int co0 = cog * 64;
    const int pg = t & 7, cg = t >> 3;    // pg: px group, cg: co group (0..15)
    const int pr = pg >> 2, pc = pg & 3;  // pr 0..1, pc 0..3
    const int rr0 = pr * 4;               // local out-row base
    const int c0l = pc * 4;               // local out-col base (== window base, origin -1)
    const int cocol = cg * 4;

    // ---- hoisted x staging offsets: 720 elems (4ch x 10r x 18c), e = t+128k
    int xsrc[6], xdst[6];
#pragma unroll
    for (int k = 0; k < 6; ++k) {
        int e = t + 128 * k;
        int cc = e / 180, rem = e % 180;
        int ir = rem / 18, ic = rem % 18;
        int gy = ty0 - 1 + ir, gx = tx0 - 1 + ic;
        bool v = (e < 720) && (gy >= 0) && (gy < HH) && (gx >= 0) && (gx < WW);
        xsrc[k] = v ? (cc * NPIX + gy * WW + gx) : -1;
        xdst[k] = cc * 200 + ir * 20 + ic;
    }
    // ---- hoisted w staging: 576 f4 (64co x 9 f4 of the 36-float [4ci x 9tap] run)
    int wbase[5], wdst0[5];
#pragma unroll
    for (int k = 0; k < 5; ++k) {
        int e = t + 128 * k;
        int co = e / 9, f = e - co * 9;
        bool v = (e < 576);
        wbase[k] = v ? ((co0 + co) * (CIN * 9) + f * 4) : -1;
        wdst0[k] = f * 256 + co;          // + j*64 for j=0..3
    }

    float4 acc[4][4];
#pragma unroll
    for (int r = 0; r < 4; ++r)
#pragma unroll
        for (int c = 0; c < 4; ++c) acc[r][c] = make_float4(0.f, 0.f, 0.f, 0.f);

    for (int ci0 = 0; ci0 < CIN; ci0 += 4) {
        __syncthreads();
        const float* xp = x + (size_t)ci0 * NPIX;
#pragma unroll
        for (int k = 0; k < 6; ++k) {
            float v = (xsrc[k] >= 0) ? xp[xsrc[k]] : 0.f;
            if (k < 5 || t < 80) xs[xdst[k]] = v;   // e<720 guard
        }
        const int wo = ci0 * 9;
#pragma unroll
        for (int k = 0; k < 5; ++k) {
            if (wbase[k] >= 0) {
                float4 wv = *(const float4*)&w1[wbase[k] + wo];
                ws[wdst0[k]]       = wv.x;
                ws[wdst0[k] + 64]  = wv.y;
                ws[wdst0[k] + 128] = wv.z;
                ws[wdst0[k] + 192] = wv.w;
            }
        }
        __syncthreads();
#pragma unroll
        for (int cc = 0; cc < 4; ++cc) {
            float xw[6][6];
#pragma unroll
            for (int i = 0; i < 6; ++i) {
                const float* row = &xs[cc * 200 + (rr0 + i) * 20 + c0l];
                float4 a = *(const float4*)row;
                float2 b = *(const float2*)(row + 4);
                xw[i][0] = a.x; xw[i][1] = a.y; xw[i][2] = a.z; xw[i][3] = a.w;
                xw[i][4] = b.x; xw[i][5] = b.y;
            }
#pragma unroll
            for (int kh = 0; kh < 3; ++kh)
#pragma unroll
                for (int kw = 0; kw < 3; ++kw) {
                    float4 wv = *(const float4*)&ws[(cc * 9 + kh * 3 + kw) * 64 + cocol];
#pragma unroll
                    for (int r = 0; r < 4; ++r)
#pragma unroll
                        for (int c = 0; c < 4; ++c) {
                            float xv = xw[r + kh][c + kw];
                            acc[r][c].x += xv * wv.x;
                            acc[r][c].y += xv * wv.y;
                            acc[r][c].z += xv * wv.z;
                            acc[r][c].w += xv * wv.w;
                        }
                }
        }
    }

    // ---- epilogue: bias + relu + f4 stores (4 px cols per store)
    const float4 bv = *(const float4*)&b1[co0 + cocol];
    const float bq[4] = {bv.x, bv.y, bv.z, bv.w};
    const int gx0 = tx0 + c0l;
    if (gx0 < WW) {
#pragma unroll
        for (int r = 0; r < 4; ++r) {
            int gy = ty0 + rr0 + r;
            if (gy < HH) {
#pragma unroll
                for (int q = 0; q < 4; ++q) {
                    float4 o;
                    o.x = fmaxf(((const float*)&acc[r][0])[q] + bq[q], 0.f);
                    o.y = fmaxf(((const float*)&acc[r][1])[q] + bq[q], 0.f);
                    o.z = fmaxf(((const float*)&acc[r][2])[q] + bq[q], 0.f);
                    o.w = fmaxf(((const float*)&acc[r][3])[q] + bq[q], 0.f);
                    *(float4*)&y[(size_t)(co0 + cocol + q) * NPIX + gy * WW + gx0] = o;
                }
            }
        }
    }
}

// ---------------------------------------------------------------------------
// Kernel 2: fused 1x1 convs (cls 9ch + box 36ch) + sigmoid + box decode +
// clip + sort-key pack. One thread per anchor; grid padded to SORTN.
// ---------------------------------------------------------------------------
__global__ __launch_bounds__(256) void rpn_head(
    const float* __restrict__ y,
    const float* __restrict__ wcls, const float* __restrict__ bcls,
    const float* __restrict__ wbox, const float* __restrict__ bbox,
    const float* __restrict__ am, const int* __restrict__ ishape,
    float* __restrict__ out_scores, float* __restrict__ out_deltas,
    float4* __restrict__ boxes, unsigned long long* __restrict__ keys)
{
    __shared__ float wlds[8][46];
    const int t = threadIdx.x;
    const int i = blockIdx.x * 256 + t;
    if (blockIdx.x * 256 >= NANCH) {       // pure padding block
        if (i < SORTN) keys[i] = 0ull;
        return;
    }
    const int ia = (i < NANCH) ? i : (NANCH - 1);
    const int p = ia / NA, a = ia % NA;
    float acc[5] = {0.f, 0.f, 0.f, 0.f, 0.f};
    for (int c0 = 0; c0 < CIN; c0 += 8) {
        __syncthreads();
        for (int e = t; e < 360; e += 256) {
            int ch = e % 45, cc = e / 45;
            wlds[cc][ch] = (ch < 9) ? wcls[ch * CIN + c0 + cc]
                                    : wbox[(ch - 9) * CIN + c0 + cc];
        }
        __syncthreads();
#pragma unroll
        for (int cc = 0; cc < 8; ++cc) {
            float yv = y[(size_t)(c0 + cc) * NPIX + p];
            acc[0] += yv * wlds[cc][a];
#pragma unroll
            for (int c = 0; c < 4; ++c)
                acc[1 + c] += yv * wlds[cc][9 + 4 * a + c];
        }
    }
    if (i >= NANCH) { if (i < SORTN) keys[i] = 0ull; return; }

    float logit = acc[0] + bcls[a];
    float score = 1.f / (1.f + expf(-logit));
    float d0 = acc[1] + bbox[4 * a + 0];
    float d1 = acc[2] + bbox[4 * a + 1];
    float d2 = acc[3] + bbox[4 * a + 2];
    float d3 = acc[4] + bbox[4 * a + 3];
    out_scores[i] = score;
    out_deltas[i * 4 + 0] = d0;
    out_deltas[i * 4 + 1] = d1;
    out_deltas[i * 4 + 2] = d2;
    out_deltas[i * 4 + 3] = d3;

    float cy = am[i * 4 + 0], cx = am[i * 4 + 1];
    float ah = am[i * 4 + 2], aw = am[i * 4 + 3];
    float ctry = cy + d0 * ah, ctrx = cx + d1 * aw;
    float hh = ah * expf(d2), ww = aw * expf(d3);
    float y1 = ctry - 0.5f * hh, x1 = ctrx - 0.5f * ww;
    float y2 = ctry + 0.5f * hh, x2 = ctrx + 0.5f * ww;
    float imh = (float)ishape[1], imw = (float)ishape[2];
    y1 = fmaxf(y1, 0.f); x1 = fmaxf(x1, 0.f);
    y2 = fminf(y2, imh); x2 = fminf(x2, imw);
    boxes[i] = make_float4(y1, x1, y2, x2);
    unsigned sb = __float_as_uint(score);  // score > 0 -> monotone bits
    keys[i] = ((unsigned long long)sb << 32) | (unsigned)i;  // tie: idx desc
}

// ---------------------------------------------------------------------------
// Bitonic sort (descending) of SORTN u64 keys.
// ---------------------------------------------------------------------------
__global__ __launch_bounds__(256) void bitonic_local(unsigned long long* keys)
{
    __shared__ unsigned long long s[2048];
    const int base = blockIdx.x * 2048, t = threadIdx.x;
    for (int k = t; k < 2048; k += 256) s[k] = keys[base + k];
    for (int L = 2; L <= 2048; L <<= 1) {
        for (int d = L >> 1; d >= 1; d >>= 1) {
            __syncthreads();
            for (int pr = t; pr < 1024; pr += 256) {
                int i = ((pr & ~(d - 1)) << 1) | (pr & (d - 1));
                int j = i + d;
                bool desc = (((base + i) & L) == 0);
                unsigned long long va = s[i], vb = s[j];
                bool sw = desc ? (va < vb) : (va > vb);
                if (sw) { s[i] = vb; s[j] = va; }
            }
        }
    }
    __syncthreads();
    for (int k = t; k < 2048; k += 256) keys[base + k] = s[k];
}

__global__ __launch_bounds__(256) void bitonic_gpass(unsigned long long* keys, int L, int d)
{
    int pr = blockIdx.x * 256 + threadIdx.x;       // SORTN/2 pairs
    int i = ((pr & ~(d - 1)) << 1) | (pr & (d - 1));
    int j = i + d;
    bool desc = ((i & L) == 0);
    unsigned long long va = keys[i], vb = keys[j];
    bool sw = desc ? (va < vb) : (va > vb);
    if (sw) { keys[i] = vb; keys[j] = va; }
}

__global__ __launch_bounds__(256) void bitonic_lmerge(unsigned long long* keys, int L)
{
    __shared__ unsigned long long s[2048];
    const int base = blockIdx.x * 2048, t = threadIdx.x;
    for (int k = t; k < 2048; k += 256) s[k] = keys[base + k];
    const bool desc = ((base & L) == 0);
    for (int d = 1024; d >= 1; d >>= 1) {
        __syncthreads();
        for (int pr = t; pr < 1024; pr += 256) {
            int i = ((pr & ~(d - 1)) << 1) | (pr & (d - 1));
            int j = i + d;
            unsigned long long va = s[i], vb = s[j];
            bool sw = desc ? (va < vb) : (va > vb);
            if (sw) { s[i] = vb; s[j] = va; }
        }
    }
    __syncthreads();
    for (int k = t; k < 2048; k += 256) keys[base + k] = s[k];
}

// ---------------------------------------------------------------------------
// Gather top-6000 boxes in sorted order; validity bitmask via ballot.
// ---------------------------------------------------------------------------
__global__ __launch_bounds__(256) void gather_sorted(
    const unsigned long long* __restrict__ keys, const float4* __restrict__ boxes,
    float4* __restrict__ box_s, unsigned long long* __restrict__ validw)
{
    int s = blockIdx.x * 256 + threadIdx.x;        // 24 blocks -> 6144
    bool valid = false;
    if (s < PRE) {
        unsigned idx = (unsigned)(keys[s] & 0xffffffffull);
        float4 b = boxes[idx];
        box_s[s] = b;
        valid = ((b.z - b.x) >= 16.f) && ((b.w - b.y) >= 16.f);
    }
    unsigned long long bal = __ballot(valid);
    if ((threadIdx.x & 63) == 0) validw[s >> 6] = bal;
}

// ---------------------------------------------------------------------------
// Suppression bitmask: mask[i] bit j = (IOU(i,j) > 0.7) && (j > i)
// ---------------------------------------------------------------------------
__global__ __launch_bounds__(128) void nms_mask(
    const float4* __restrict__ box_s, unsigned long long* __restrict__ mask)
{
    const int i = blockIdx.x;
    const int w = threadIdx.x;
    if (w >= NW) return;
    float4 bi = box_s[i];
    float areai = (bi.z - bi.x) * (bi.w - bi.y);
    unsigned long long m = 0ull;
    const int j0 = w * 64;
    if (j0 + 63 > i) {
#pragma unroll 4
        for (int b = 0; b < 64; ++b) {
            int j = j0 + b;
            if (j <= i || j >= PRE) continue;
            float4 bj = box_s[j];
            float areaj = (bj.z - bj.x) * (bj.w - bj.y);
            float iy1 = fmaxf(bi.x, bj.x), ix1 = fmaxf(bi.y, bj.y);
            float iy2 = fminf(bi.z, bj.z), ix2 = fminf(bi.w, bj.w);
            float inter = fmaxf(iy2 - iy1, 0.f) * fmaxf(ix2 - ix1, 0.f);
            float iou = inter / (areai + areaj - inter + 1e-8f);
            if (iou > 0.7f) m |= (1ull << b);
        }
    }
    mask[(size_t)i * MASKW + w] = m;
}

// ---------------------------------------------------------------------------
// Sequential greedy NMS scan. Single wave; removed-set in 2 regs/lane.
// ---------------------------------------------------------------------------
__global__ __launch_bounds__(64) void nms_scan(
    const unsigned long long* __restrict__ mask,
    const unsigned long long* __restrict__ validw,
    unsigned long long* __restrict__ keepw)
{
    const int l = threadIdx.x;
    unsigned long long r0 = ~validw[l];
    unsigned long long r1 = (l < NW - 64) ? ~validw[64 + l] : ~0ull;

    unsigned long long p0[16], p1[16];
#pragma unroll
    for (int k = 0; k < 16; ++k) {
        p0[k] = mask[(size_t)k * MASKW + l];
        p1[k] = (l < NW - 64) ? mask[(size_t)k * MASKW + 64 + l] : 0ull;
    }
    int kept = 0;
    for (int w = 0; w < NW && kept < POST; ++w) {
        unsigned long long Wc = (w < 64) ? __shfl(r0, w) : __shfl(r1, w - 64);
#pragma unroll 16
        for (int b = 0; b < 64; ++b) {
            int i = w * 64 + b;
            if (i >= PRE) break;
            int slot = i & 15;
            unsigned long long m0 = p0[slot], m1 = p1[slot];
            int nxt = i + 16;
            if (nxt < PRE) {
                p0[slot] = mask[(size_t)nxt * MASKW + l];
                p1[slot] = (l < NW - 64) ? mask[(size_t)nxt * MASKW + 64 + l] : 0ull;
            }
            if (!((Wc >> b) & 1ull)) {
                r0 |= m0; r1 |= m1;
                Wc = (w < 64) ? __shfl(r0, w) : __shfl(r1, w - 64);
                ++kept;
            }
        }
    }
    keepw[l] = ~r0;
    if (l < NW - 64) keepw[64 + l] = ~r1;
}

// ---------------------------------------------------------------------------
// Emit first POST kept boxes in order; zero-fill rest.
// ---------------------------------------------------------------------------
__global__ __launch_bounds__(256) void out_gather(
    const unsigned long long* __restrict__ keepw,
    const float4* __restrict__ box_s, float* __restrict__ outp)
{
    __shared__ unsigned long long kw_s[NW];
    __shared__ int prefix[NW];
    const int t = threadIdx.x;
    if (t < NW) kw_s[t] = keepw[t];
    __syncthreads();
    if (t == 0) {
        int cum = 0;
        for (int w = 0; w < NW; ++w) { prefix[w] = cum; cum += __popcll(kw_s[w]); }
    }
    for (int k = t; k < POST * 4; k += 256) outp[k] = 0.f;
    __syncthreads();
    for (int i = t; i < PRE; i += 256) {
        int w = i >> 6, b = i & 63;
        unsigned long long kw = kw_s[w];
        if ((kw >> b) & 1ull) {
            int rank = prefix[w] + __popcll(kw & ((1ull << b) - 1ull));
            if (rank < POST) {
                float4 bx = box_s[i];
                outp[rank * 4 + 0] = bx.x;
                outp[rank * 4 + 1] = bx.y;
                outp[rank * 4 + 2] = bx.z;
                outp[rank * 4 + 3] = bx.w;
            }
        }
    }
}

// ---------------------------------------------------------------------------
extern "C" void kernel_launch(void* const* d_in, const int* in_sizes, int n_in,
                              void* d_out, int out_size, void* d_ws, size_t ws_size,
                              hipStream_t stream)
{
    const float* x      = (const float*)d_in[0];
    const int*   ishape = (const int*)  d_in[1];
    const float* am     = (const float*)d_in[2];
    const float* w1   = (const float*)d_in[6];
    const float* b1   = (const float*)d_in[7];
    const float* wcls = (const float*)d_in[8];
    const float* bcls = (const float*)d_in[9];
    const float* wbox = (const float*)d_in[10];
    const float* bbox = (const float*)d_in[11];
    float* out = (float*)d_out;

    char* ws = (char*)d_ws;
    size_t off = 0;
    float* y = (float*)(ws + off);                    off += (size_t)COUT * NPIX * 4;
    float4* boxes = (float4*)(ws + off);              off += (size_t)NANCH * 16;
    unsigned long long* keys = (unsigned long long*)(ws + off); off += (size_t)SORTN * 8;
    float4* box_s = (float4*)(ws + off);              off += (size_t)PRE * 16;
    unsigned long long* validw = (unsigned long long*)(ws + off); off += 96 * 8;
    unsigned long long* keepw  = (unsigned long long*)(ws + off); off += 96 * 8;
    unsigned long long* maskb  = (unsigned long long*)(ws + off); off += (size_t)PRE * MASKW * 8;

    conv3x3_relu<<<dim3(16, NTR * NTC), 128, 0, stream>>>(x, w1, b1, y);
    rpn_head<<<SORTN / 256, 256, 0, stream>>>(y, wcls, bcls, wbox, bbox, am, ishape,
                                              out, out + NANCH, boxes, keys);
    bitonic_local<<<SORTN / 2048, 256, 0, stream>>>(keys);
    for (int L = 4096; L <= SORTN; L <<= 1) {
        for (int d = L >> 1; d >= 2048; d >>= 1)
            bitonic_gpass<<<SORTN / 512, 256, 0, stream>>>(keys, L, d);
        bitonic_lmerge<<<SORTN / 2048, 256, 0, stream>>>(keys, L);
    }
    gather_sorted<<<24, 256, 0, stream>>>(keys, boxes, box_s, validw);
    nms_mask<<<PRE, 128, 0, stream>>>(box_s, maskb);
    nms_scan<<<1, 64, 0, stream>>>(maskb, validw, keepw);
    out_gather<<<1, 256, 0, stream>>>(keepw, box_s, out + (size_t)NANCH * 5);
}

// Round 3
// 3719.241 us; speedup vs baseline: 1.1877x; 1.0774x over previous
//
#include <hip/hip_runtime.h>
#include <stdint.h>

#define HH 100
#define WW 100
#define NPIX 10000
#define CIN 1024
#define COUT 1024
#define NA 9
#define NANCH 90000
#define PRE 6000
#define POST 300
#define SORTN 131072
#define MASKW 96
#define NW 94
#define K9 9216   // CIN*9

// ---------------------------------------------------------------------------
// Kernel 0: transpose w1 [co][ci*9+tap] -> wt [ci*9+tap][co]. LDS-tiled.
// ---------------------------------------------------------------------------
__global__ __launch_bounds__(256) void wtrans(
    const float* __restrict__ w1, float* __restrict__ wt)
{
    __shared__ float s[32][33];
    const int tx = threadIdx.x & 31;         // k within tile
    const int ty = threadIdx.x >> 5;         // 0..7
    const int kb = blockIdx.x;               // 288 tiles of k
    const int cb = blockIdx.y;               // 32 tiles of co
#pragma unroll
    for (int i = 0; i < 4; ++i) {
        int co = cb * 32 + ty + i * 8;
        s[ty + i * 8][tx] = w1[(size_t)co * K9 + kb * 32 + tx];
    }
    __syncthreads();
#pragma unroll
    for (int i = 0; i < 4; ++i) {
        int k = kb * 32 + ty + i * 8;
        wt[(size_t)k * COUT + cb * 32 + tx] = s[tx][ty + i * 8];
    }
}

// ---------------------------------------------------------------------------
// Kernel 1: 3x3 conv (1024->1024, SAME) + bias + ReLU. fp32.
// Block: 8x8 px x 128 co, 256 thr. Per-thread: 4 px x 8 co = 32 scalar accs.
// Weights pre-transposed (wt[k][co]) -> coalesced, conflict-free staging.
// ---------------------------------------------------------------------------
__global__ __launch_bounds__(256, 4) void conv3x3_relu(
    const float* __restrict__ x, const float* __restrict__ wt,
    const float* __restrict__ b1, float* __restrict__ y)
{
    __shared__ __align__(16) float xs[2][10][12];    // 2 ci x 10x10 halo, pitch 12
    __shared__ __align__(16) float ws[18][128];      // [cc*9+tap][co]
    const int t    = threadIdx.x;
    const int cog  = blockIdx.x;              // 0..7 -> 128-co tile
    const int tile = blockIdx.y;              // 0..168 -> 8x8 px tile (13x13)
    const int ty0 = (tile / 13) * 8;
    const int tx0 = (tile % 13) * 8;
    const int co0 = cog * 128;
    const int g   = t & 15;                   // co group: quads g*4 and g*4+64
    const int q   = t >> 4;                   // 0..15
    const int py  = q >> 1;                   // 0..7 local row
    const int px4 = (q & 1) * 4;              // 0 or 4 local col base

    // hoisted x-staging offsets (200 elems, t<200)
    int xsrc = -1, xdst = 0;
    if (t < 200) {
        int cc = t / 100, rem = t % 100;
        int ir = rem / 10, ic = rem % 10;
        int gy = ty0 - 1 + ir, gx = tx0 - 1 + ic;
        xdst = cc * 120 + ir * 12 + ic;
        if (gy >= 0 && gy < HH && gx >= 0 && gx < WW)
            xsrc = cc * NPIX + gy * WW + gx;
    }
    // hoisted w-staging offsets: 576 f4 chunks, e = t + 256k (k=0..2)
    // row = e>>5 (0..17 = cc*9+tap), colf4 = e&31
    int wrow[3], wcol[3];
#pragma unroll
    for (int k = 0; k < 3; ++k) {
        int e = t + 256 * k;
        wrow[k] = e >> 5;
        wcol[k] = (e & 31) * 4;
    }

    float acc[4][2][4];                       // [px col][co half][co sub]
#pragma unroll
    for (int c = 0; c < 4; ++c)
#pragma unroll
        for (int h = 0; h < 2; ++h)
#pragma unroll
            for (int j = 0; j < 4; ++j) acc[c][h][j] = 0.f;

    for (int ci0 = 0; ci0 < CIN; ci0 += 2) {
        __syncthreads();
        if (t < 200) {
            float v = (xsrc >= 0) ? x[(size_t)ci0 * NPIX + xsrc] : 0.f;
            ((float*)xs)[xdst] = v;
        }
        {
            const float* wp = wt + (size_t)ci0 * 9 * COUT + co0;
#pragma unroll
            for (int k = 0; k < 3; ++k) {
                if (k < 2 || t < 64) {
                    float4 wv = *(const float4*)&wp[(size_t)wrow[k] * COUT + wcol[k]];
                    *(float4*)&ws[wrow[k]][wcol[k]] = wv;
                }
            }
        }
        __syncthreads();
#pragma unroll
        for (int cc = 0; cc < 2; ++cc) {
#pragma unroll
            for (int kh = 0; kh < 3; ++kh) {
                float x6[6];
                {
                    const float* row = &xs[cc][py + kh][px4];
                    float4 a = *(const float4*)row;
                    float2 b = *(const float2*)(row + 4);
                    x6[0] = a.x; x6[1] = a.y; x6[2] = a.z; x6[3] = a.w;
                    x6[4] = b.x; x6[5] = b.y;
                }
#pragma unroll
                for (int kw = 0; kw < 3; ++kw) {
                    const int tap = cc * 9 + kh * 3 + kw;
                    float4 w0 = *(const float4*)&ws[tap][g * 4];
                    float4 w1v = *(const float4*)&ws[tap][g * 4 + 64];
#pragma unroll
                    for (int c = 0; c < 4; ++c) {
                        float xv = x6[c + kw];
                        acc[c][0][0] += xv * w0.x;
                        acc[c][0][1] += xv * w0.y;
                        acc[c][0][2] += xv * w0.z;
                        acc[c][0][3] += xv * w0.w;
                        acc[c][1][0] += xv * w1v.x;
                        acc[c][1][1] += xv * w1v.y;
                        acc[c][1][2] += xv * w1v.z;
                        acc[c][1][3] += xv * w1v.w;
                    }
                }
            }
        }
    }

    // epilogue: bias + relu + f4 stores (4 px per store)
    const int gy = ty0 + py;
    const int gx0 = tx0 + px4;
    if (gy < HH && gx0 < WW) {
        float4 b0 = *(const float4*)&b1[co0 + g * 4];
        float4 b1v = *(const float4*)&b1[co0 + g * 4 + 64];
        const float bb[2][4] = {{b0.x, b0.y, b0.z, b0.w}, {b1v.x, b1v.y, b1v.z, b1v.w}};
#pragma unroll
        for (int h = 0; h < 2; ++h)
#pragma unroll
            for (int j = 0; j < 4; ++j) {
                float4 o;
                o.x = fmaxf(acc[0][h][j] + bb[h][j], 0.f);
                o.y = fmaxf(acc[1][h][j] + bb[h][j], 0.f);
                o.z = fmaxf(acc[2][h][j] + bb[h][j], 0.f);
                o.w = fmaxf(acc[3][h][j] + bb[h][j], 0.f);
                int co = co0 + g * 4 + j + h * 64;
                *(float4*)&y[(size_t)co * NPIX + gy * WW + gx0] = o;
            }
    }
}

// ---------------------------------------------------------------------------
// Kernel 2: fused 1x1 heads + sigmoid + box decode + clip + sort-key pack.
// ---------------------------------------------------------------------------
__global__ __launch_bounds__(256) void rpn_head(
    const float* __restrict__ y,
    const float* __restrict__ wcls, const float* __restrict__ bcls,
    const float* __restrict__ wbox, const float* __restrict__ bbox,
    const float* __restrict__ am, const int* __restrict__ ishape,
    float* __restrict__ out_scores, float* __restrict__ out_deltas,
    float4* __restrict__ boxes, unsigned long long* __restrict__ keys)
{
    __shared__ float wlds[8][46];
    const int t = threadIdx.x;
    const int i = blockIdx.x * 256 + t;
    if (blockIdx.x * 256 >= NANCH) {
        if (i < SORTN) keys[i] = 0ull;
        return;
    }
    const int ia = (i < NANCH) ? i : (NANCH - 1);
    const int p = ia / NA, a = ia % NA;
    float acc[5] = {0.f, 0.f, 0.f, 0.f, 0.f};
    for (int c0 = 0; c0 < CIN; c0 += 8) {
        __syncthreads();
        for (int e = t; e < 360; e += 256) {
            int ch = e % 45, cc = e / 45;
            wlds[cc][ch] = (ch < 9) ? wcls[ch * CIN + c0 + cc]
                                    : wbox[(ch - 9) * CIN + c0 + cc];
        }
        __syncthreads();
#pragma unroll
        for (int cc = 0; cc < 8; ++cc) {
            float yv = y[(size_t)(c0 + cc) * NPIX + p];
            acc[0] += yv * wlds[cc][a];
#pragma unroll
            for (int c = 0; c < 4; ++c)
                acc[1 + c] += yv * wlds[cc][9 + 4 * a + c];
        }
    }
    if (i >= NANCH) { if (i < SORTN) keys[i] = 0ull; return; }

    float logit = acc[0] + bcls[a];
    float score = 1.f / (1.f + expf(-logit));
    float d0 = acc[1] + bbox[4 * a + 0];
    float d1 = acc[2] + bbox[4 * a + 1];
    float d2 = acc[3] + bbox[4 * a + 2];
    float d3 = acc[4] + bbox[4 * a + 3];
    out_scores[i] = score;
    out_deltas[i * 4 + 0] = d0;
    out_deltas[i * 4 + 1] = d1;
    out_deltas[i * 4 + 2] = d2;
    out_deltas[i * 4 + 3] = d3;

    float cy = am[i * 4 + 0], cx = am[i * 4 + 1];
    float ah = am[i * 4 + 2], aw = am[i * 4 + 3];
    float ctry = cy + d0 * ah, ctrx = cx + d1 * aw;
    float hh = ah * expf(d2), ww = aw * expf(d3);
    float y1 = ctry - 0.5f * hh, x1 = ctrx - 0.5f * ww;
    float y2 = ctry + 0.5f * hh, x2 = ctrx + 0.5f * ww;
    float imh = (float)ishape[1], imw = (float)ishape[2];
    y1 = fmaxf(y1, 0.f); x1 = fmaxf(x1, 0.f);
    y2 = fminf(y2, imh); x2 = fminf(x2, imw);
    boxes[i] = make_float4(y1, x1, y2, x2);
    unsigned sb = __float_as_uint(score);
    keys[i] = ((unsigned long long)sb << 32) | (unsigned)i;
}

// ---------------------------------------------------------------------------
// Bitonic sort (descending) of SORTN u64 keys.
// ---------------------------------------------------------------------------
__global__ __launch_bounds__(256) void bitonic_local(unsigned long long* keys)
{
    __shared__ unsigned long long s[2048];
    const int base = blockIdx.x * 2048, t = threadIdx.x;
    for (int k = t; k < 2048; k += 256) s[k] = keys[base + k];
    for (int L = 2; L <= 2048; L <<= 1) {
        for (int d = L >> 1; d >= 1; d >>= 1) {
            __syncthreads();
            for (int pr = t; pr < 1024; pr += 256) {
                int i = ((pr & ~(d - 1)) << 1) | (pr & (d - 1));
                int j = i + d;
                bool desc = (((base + i) & L) == 0);
                unsigned long long va = s[i], vb = s[j];
                bool sw = desc ? (va < vb) : (va > vb);
                if (sw) { s[i] = vb; s[j] = va; }
            }
        }
    }
    __syncthreads();
    for (int k = t; k < 2048; k += 256) keys[base + k] = s[k];
}

__global__ __launch_bounds__(256) void bitonic_gpass(unsigned long long* keys, int L, int d)
{
    int pr = blockIdx.x * 256 + threadIdx.x;
    int i = ((pr & ~(d - 1)) << 1) | (pr & (d - 1));
    int j = i + d;
    bool desc = ((i & L) == 0);
    unsigned long long va = keys[i], vb = keys[j];
    bool sw = desc ? (va < vb) : (va > vb);
    if (sw) { keys[i] = vb; keys[j] = va; }
}

__global__ __launch_bounds__(256) void bitonic_lmerge(unsigned long long* keys, int L)
{
    __shared__ unsigned long long s[2048];
    const int base = blockIdx.x * 2048, t = threadIdx.x;
    for (int k = t; k < 2048; k += 256) s[k] = keys[base + k];
    const bool desc = ((base & L) == 0);
    for (int d = 1024; d >= 1; d >>= 1) {
        __syncthreads();
        for (int pr = t; pr < 1024; pr += 256) {
            int i = ((pr & ~(d - 1)) << 1) | (pr & (d - 1));
            int j = i + d;
            unsigned long long va = s[i], vb = s[j];
            bool sw = desc ? (va < vb) : (va > vb);
            if (sw) { s[i] = vb; s[j] = va; }
        }
    }
    __syncthreads();
    for (int k = t; k < 2048; k += 256) keys[base + k] = s[k];
}

// ---------------------------------------------------------------------------
__global__ __launch_bounds__(256) void gather_sorted(
    const unsigned long long* __restrict__ keys, const float4* __restrict__ boxes,
    float4* __restrict__ box_s, unsigned long long* __restrict__ validw)
{
    int s = blockIdx.x * 256 + threadIdx.x;
    bool valid = false;
    if (s < PRE) {
        unsigned idx = (unsigned)(keys[s] & 0xffffffffull);
        float4 b = boxes[idx];
        box_s[s] = b;
        valid = ((b.z - b.x) >= 16.f) && ((b.w - b.y) >= 16.f);
    }
    unsigned long long bal = __ballot(valid);
    if ((threadIdx.x & 63) == 0) validw[s >> 6] = bal;
}

// ---------------------------------------------------------------------------
__global__ __launch_bounds__(128) void nms_mask(
    const float4* __restrict__ box_s, unsigned long long* __restrict__ mask)
{
    const int i = blockIdx.x;
    const int w = threadIdx.x;
    if (w >= NW) return;
    float4 bi = box_s[i];
    float areai = (bi.z - bi.x) * (bi.w - bi.y);
    unsigned long long m = 0ull;
    const int j0 = w * 64;
    if (j0 + 63 > i) {
#pragma unroll 4
        for (int b = 0; b < 64; ++b) {
            int j = j0 + b;
            if (j <= i || j >= PRE) continue;
            float4 bj = box_s[j];
            float areaj = (bj.z - bj.x) * (bj.w - bj.y);
            float iy1 = fmaxf(bi.x, bj.x), ix1 = fmaxf(bi.y, bj.y);
            float iy2 = fminf(bi.z, bj.z), ix2 = fminf(bi.w, bj.w);
            float inter = fmaxf(iy2 - iy1, 0.f) * fmaxf(ix2 - ix1, 0.f);
            float iou = inter / (areai + areaj - inter + 1e-8f);
            if (iou > 0.7f) m |= (1ull << b);
        }
    }
    mask[(size_t)i * MASKW + w] = m;
}

// ---------------------------------------------------------------------------
__global__ __launch_bounds__(64) void nms_scan(
    const unsigned long long* __restrict__ mask,
    const unsigned long long* __restrict__ validw,
    unsigned long long* __restrict__ keepw)
{
    const int l = threadIdx.x;
    unsigned long long r0 = ~validw[l];
    unsigned long long r1 = (l < NW - 64) ? ~validw[64 + l] : ~0ull;

    unsigned long long p0[16], p1[16];
#pragma unroll
    for (int k = 0; k < 16; ++k) {
        p0[k] = mask[(size_t)k * MASKW + l];
        p1[k] = (l < NW - 64) ? mask[(size_t)k * MASKW + 64 + l] : 0ull;
    }
    int kept = 0;
    for (int w = 0; w < NW && kept < POST; ++w) {
        unsigned long long Wc = (w < 64) ? __shfl(r0, w) : __shfl(r1, w - 64);
#pragma unroll 16
        for (int b = 0; b < 64; ++b) {
            int i = w * 64 + b;
            if (i >= PRE) break;
            int slot = i & 15;
            unsigned long long m0 = p0[slot], m1 = p1[slot];
            int nxt = i + 16;
            if (nxt < PRE) {
                p0[slot] = mask[(size_t)nxt * MASKW + l];
                p1[slot] = (l < NW - 64) ? mask[(size_t)nxt * MASKW + 64 + l] : 0ull;
            }
            if (!((Wc >> b) & 1ull)) {
                r0 |= m0; r1 |= m1;
                Wc = (w < 64) ? __shfl(r0, w) : __shfl(r1, w - 64);
                ++kept;
            }
        }
    }
    keepw[l] = ~r0;
    if (l < NW - 64) keepw[64 + l] = ~r1;
}

// ---------------------------------------------------------------------------
__global__ __launch_bounds__(256) void out_gather(
    const unsigned long long* __restrict__ keepw,
    const float4* __restrict__ box_s, float* __restrict__ outp)
{
    __shared__ unsigned long long kw_s[NW];
    __shared__ int prefix[NW];
    const int t = threadIdx.x;
    if (t < NW) kw_s[t] = keepw[t];
    __syncthreads();
    if (t == 0) {
        int cum = 0;
        for (int w = 0; w < NW; ++w) { prefix[w] = cum; cum += __popcll(kw_s[w]); }
    }
    for (int k = t; k < POST * 4; k += 256) outp[k] = 0.f;
    __syncthreads();
    for (int i = t; i < PRE; i += 256) {
        int w = i >> 6, b = i & 63;
        unsigned long long kw = kw_s[w];
        if ((kw >> b) & 1ull) {
            int rank = prefix[w] + __popcll(kw & ((1ull << b) - 1ull));
            if (rank < POST) {
                float4 bx = box_s[i];
                outp[rank * 4 + 0] = bx.x;
                outp[rank * 4 + 1] = bx.y;
                outp[rank * 4 + 2] = bx.z;
                outp[rank * 4 + 3] = bx.w;
            }
        }
    }
}

// ---------------------------------------------------------------------------
extern "C" void kernel_launch(void* const* d_in, const int* in_sizes, int n_in,
                              void* d_out, int out_size, void* d_ws, size_t ws_size,
                              hipStream_t stream)
{
    const float* x      = (const float*)d_in[0];
    const int*   ishape = (const int*)  d_in[1];
    const float* am     = (const float*)d_in[2];
    const float* w1   = (const float*)d_in[6];
    const float* b1   = (const float*)d_in[7];
    const float* wcls = (const float*)d_in[8];
    const float* bcls = (const float*)d_in[9];
    const float* wbox = (const float*)d_in[10];
    const float* bbox = (const float*)d_in[11];
    float* out = (float*)d_out;

    char* ws = (char*)d_ws;
    size_t off = 0;
    float* y = (float*)(ws + off);                    off += (size_t)COUT * NPIX * 4;
    float* wt = (float*)(ws + off);                   off += (size_t)K9 * COUT * 4;   // 37.75 MB
    float4* boxes = (float4*)(ws + off);              off += (size_t)NANCH * 16;
    unsigned long long* keys = (unsigned long long*)(ws + off); off += (size_t)SORTN * 8;
    float4* box_s = (float4*)(ws + off);              off += (size_t)PRE * 16;
    unsigned long long* validw = (unsigned long long*)(ws + off); off += 96 * 8;
    unsigned long long* keepw  = (unsigned long long*)(ws + off); off += 96 * 8;
    unsigned long long* maskb  = (unsigned long long*)(ws + off); off += (size_t)PRE * MASKW * 8;

    wtrans<<<dim3(K9 / 32, COUT / 32), 256, 0, stream>>>(w1, wt);
    conv3x3_relu<<<dim3(8, 169), 256, 0, stream>>>(x, wt, b1, y);
    rpn_head<<<SORTN / 256, 256, 0, stream>>>(y, wcls, bcls, wbox, bbox, am, ishape,
                                              out, out + NANCH, boxes, keys);
    bitonic_local<<<SORTN / 2048, 256, 0, stream>>>(keys);
    for (int L = 4096; L <= SORTN; L <<= 1) {
        for (int d = L >> 1; d >= 2048; d >>= 1)
            bitonic_gpass<<<SORTN / 512, 256, 0, stream>>>(keys, L, d);
        bitonic_lmerge<<<SORTN / 2048, 256, 0, stream>>>(keys, L);
    }
    gather_sorted<<<24, 256, 0, stream>>>(keys, boxes, box_s, validw);
    nms_mask<<<PRE, 128, 0, stream>>>(box_s, maskb);
    nms_scan<<<1, 64, 0, stream>>>(maskb, validw, keepw);
    out_gather<<<1, 256, 0, stream>>>(keepw, box_s, out + (size_t)NANCH * 5);
}